// Round 1
// baseline (426.995 us; speedup 1.0000x reference)
//
#include <hip/hip_runtime.h>

#define CDIM 512
#define NDIM 4096
#define BATCH 4

using bf8v = __attribute__((ext_vector_type(8))) __bf16;
using f4v  = __attribute__((ext_vector_type(4))) float;

typedef __attribute__((address_space(1))) unsigned int gu32;
typedef __attribute__((address_space(3))) unsigned int lu32;

static __device__ __forceinline__ unsigned short f2bf(float f) {
  unsigned int u = __float_as_uint(f);
  u += 0x7fffu + ((u >> 16) & 1u);   // round-to-nearest-even
  return (unsigned short)(u >> 16);
}

// ---------------- GN pass 1: per-(b,g) mean/rstd ----------------
__global__ __launch_bounds__(256) void gn_stats_kernel(
    const float* __restrict__ x, float* __restrict__ stats) {
  const int tid = threadIdx.x;
  const float4* xv = (const float4*)(x + (long)blockIdx.x * 65536);
  float s = 0.f, ss = 0.f;
  for (int i = tid; i < 16384; i += 256) {
    float4 d = xv[i];
    s  += d.x + d.y + d.z + d.w;
    ss += d.x * d.x + d.y * d.y + d.z * d.z + d.w * d.w;
  }
#pragma unroll
  for (int off = 32; off; off >>= 1) {
    s  += __shfl_down(s, off);
    ss += __shfl_down(ss, off);
  }
  __shared__ float red[8];
  if ((tid & 63) == 0) { red[tid >> 6] = s; red[4 + (tid >> 6)] = ss; }
  __syncthreads();
  if (tid == 0) {
    float S  = red[0] + red[1] + red[2] + red[3];
    float SS = red[4] + red[5] + red[6] + red[7];
    float mean = S * (1.f / 65536.f);
    float var  = SS * (1.f / 65536.f) - mean * mean;
    stats[blockIdx.x * 2]     = mean;
    stats[blockIdx.x * 2 + 1] = rsqrtf(var + 1e-6f);
  }
}

// ---------------- GN pass 2: normalize + transpose, fp32 [C,N] -> bf16 [N,C] ----------------
__global__ __launch_bounds__(256) void gn_transpose_kernel(
    const float* __restrict__ x, const float* __restrict__ gs,
    const float* __restrict__ gb, const float* __restrict__ stats,
    unsigned short* __restrict__ hT) {
  __shared__ float t[64][65];
  const int tid = threadIdx.x;
  const int b = blockIdx.z;
  const long bbx = (long)b * ((long)CDIM * NDIM);
  const int n0 = blockIdx.x * 64, c0 = blockIdx.y * 64;
  for (int k = 0; k < 4; ++k) {
    int it = tid + k * 256;
    int c = it >> 4, no = (it & 15) << 2;
    int ch = c0 + c;
    int g = ch >> 4;
    float mean = stats[(b * 32 + g) * 2];
    float rstd = stats[(b * 32 + g) * 2 + 1];
    float a  = rstd * gs[ch];
    float bb = gb[ch] - mean * a;
    float4 d = *(const float4*)&x[bbx + (long)ch * NDIM + n0 + no];
    t[no + 0][c] = d.x * a + bb;
    t[no + 1][c] = d.y * a + bb;
    t[no + 2][c] = d.z * a + bb;
    t[no + 3][c] = d.w * a + bb;
  }
  __syncthreads();
  const long bbh = (long)b * ((long)NDIM * CDIM);
  for (int k = 0; k < 2; ++k) {
    int it = tid + k * 256;
    int n = it >> 3, co = (it & 7) << 3;
    unsigned int ow[4];
#pragma unroll
    for (int j = 0; j < 4; ++j) {
      unsigned short lo = f2bf(t[n][co + 2 * j]);
      unsigned short hi = f2bf(t[n][co + 2 * j + 1]);
      ow[j] = (unsigned int)lo | ((unsigned int)hi << 16);
    }
    uint4 o; o.x = ow[0]; o.y = ow[1]; o.z = ow[2]; o.w = ow[3];
    *(uint4*)&hT[bbh + (long)(n0 + n) * CDIM + c0 + co] = o;
  }
}

// ---------------- merged prep: wq/wk/wv fp32->bf16 + bias concat ----------------
__global__ __launch_bounds__(256) void prep_kernel(
    const float* __restrict__ wq, const float* __restrict__ wk,
    const float* __restrict__ wv, const float* __restrict__ bq,
    const float* __restrict__ bk, unsigned short* __restrict__ wqkb,
    unsigned short* __restrict__ wvb, float* __restrict__ bqk) {
  int blk = blockIdx.x;
  if (blk < 768) {
    int i = blk * 256 + threadIdx.x;
    const float* src = (blk < 256) ? wq : (blk < 512) ? wk : wv;
    unsigned short* dst = (blk < 256) ? wqkb : (blk < 512) ? (wqkb + 262144) : wvb;
    int j = i - ((blk < 256) ? 0 : (blk < 512) ? 65536 : 131072);
    float4 d = ((const float4*)src)[j];
    ushort4 o;
    o.x = f2bf(d.x); o.y = f2bf(d.y); o.z = f2bf(d.z); o.w = f2bf(d.w);
    ((ushort4*)dst)[j] = o;
  } else {
#pragma unroll
    for (int k = 0; k < 4; ++k) {
      int i = threadIdx.x + k * 256;
      bqk[i] = (i < 512) ? bq[i] : bk[i - 512];
    }
  }
}

// ---------------- fp32 -> bf16 convert (wp, launched late) ----------------
__global__ __launch_bounds__(256) void cvt_kernel(
    const float* __restrict__ src, unsigned short* __restrict__ dst, int n4) {
  int i = blockIdx.x * 256 + threadIdx.x;
  if (i >= n4) return;
  float4 d = ((const float4*)src)[i];
  ushort4 o;
  o.x = f2bf(d.x); o.y = f2bf(d.y); o.z = f2bf(d.z); o.w = f2bf(d.w);
  ((ushort4*)dst)[i] = o;
}

// ---------------- 8-phase NT GEMM, 8 waves, 4-slot LDS ring, counted vmcnt ----------------
// C[M,Nn] = A[M,K] * B[Nn,K]^T, bf16 operands, row strides lA/lB.
// K consumed in 32-wide chunks; chunk c lives in LDS ring slot c&3; staged 3
// chunks ahead via global_load_lds; per chunk two phases, each: [wait+]barrier,
// stage one operand of chunk d+3, ds_read frags (phase A only), setprio(1),
// MFMA half-cluster, setprio(0).  vmcnt is counted (8 or 6), drained 4->0 only
// in the last two chunks.  LDS granule-XOR swizzle (involution on both the
// staging *source* address and the fragment read) keeps ds_read_b128 conflict-free.
// EPI: 0 bf16 + bias[col]; 1 bf16 + bias[row]; 2 bf16 exp(val*scale);
//      3 bf16 val/rowsum (ones-MFMA); 4 fp32 + bias[row] + residual X.
// ORD: 0 = bx fastest in g, 1 = by fastest (L2 panel-reuse choice).
template <int BM, int BN, int EPI, int ORD>
__global__ __launch_bounds__(512, 2) void gemm8(
    const unsigned short* __restrict__ A, long sA, int lA,
    const unsigned short* __restrict__ B, long sB, int lB,
    void* __restrict__ Cp, long sC,
    const float* __restrict__ bias,
    const float* __restrict__ X, long sX,
    int GX, int GY, int Nn, int K) {
  constexpr int TM = BM / 32;          // frag rows per wave (8 or 4)
  constexpr int TN = BN / 64;          // frag cols per wave (4)
  constexpr int LA = BM / 128;         // global_load_lds per thread per A-chunk
  constexpr int LB = BN / 128;
  constexpr int VN = 2 * (LA + LB);    // steady-state vmcnt (8 or 6)

  __shared__ __align__(16) unsigned short As[4 * BM * 32];
  __shared__ __align__(16) unsigned short Bs[4 * BN * 32];

  const int tid = threadIdx.x;
  const int nwg = gridDim.x;
  // bijective XCD-chunk mapping (nwg % 8 == 0 for all launches)
  const int g = (blockIdx.x & 7) * (nwg >> 3) + (blockIdx.x >> 3);
  int bx, by, bz;
  if (ORD == 0) { bx = g % GX; int t = g / GX; by = t % GY; bz = t / GY; }
  else          { by = g % GY; int t = g / GY; bx = t % GX; bz = t / GX; }

  A += (long)bz * sA;
  B += (long)bz * sB;
  const int m0 = by * BM;
  const int n0 = bx * BN;
  const int lane = tid & 63;
  const int wv = tid >> 6;
  const int wm = (wv >> 2) * (BM / 2);
  const int wn = (wv & 3) * (BN / 4);
  const int l16 = lane & 15;
  const int quad = lane >> 4;
  const int rdo = ((quad ^ (l16 & 3)) << 3);   // fragment-read swizzled granule

  // staging: per load, 512 threads cover 128 rows x 4 granules (16B each)
  const int rl = tid >> 2;             // row within 128-row group
  const int gl = tid & 3;              // physical granule slot
  const int swl = ((gl ^ (rl & 3)) << 3);      // inverse-swizzled source granule
  const unsigned short* Ag = A + (long)(m0 + rl) * lA + swl;
  const unsigned short* Bg = B + (long)(n0 + rl) * lB + swl;
  unsigned short* Asl = As + wv * 512;         // wave-uniform LDS dest base
  unsigned short* Bsl = Bs + wv * 512;

  const int nchunk = K >> 5;

  auto stageA = [&](int c) {
    if (c < nchunk) {
#pragma unroll
      for (int i = 0; i < LA; ++i)
        __builtin_amdgcn_global_load_lds(
            (const gu32*)(Ag + (long)i * 128 * lA + c * 32),
            (lu32*)(Asl + (c & 3) * (BM * 32) + i * 4096), 16, 0, 0);
    }
  };
  auto stageB = [&](int c) {
    if (c < nchunk) {
#pragma unroll
      for (int i = 0; i < LB; ++i)
        __builtin_amdgcn_global_load_lds(
            (const gu32*)(Bg + (long)i * 128 * lB + c * 32),
            (lu32*)(Bsl + (c & 3) * (BN * 32) + i * 4096), 16, 0, 0);
    }
  };

  f4v acc[TM][TN] = {};
  f4v accr[TM] = {};                   // EPI==3 row-sums (DCE'd otherwise)
  bf8v ones;
#pragma unroll
  for (int i = 0; i < 8; ++i) ones[i] = (__bf16)1.0f;

  auto body = [&](int d) {
    __builtin_amdgcn_s_barrier();
    stageA(d + 3);
    const unsigned short* Ab = As + (d & 3) * (BM * 32);
    const unsigned short* Bb = Bs + (d & 3) * (BN * 32);
    bf8v af[TM], bf[TN];
#pragma unroll
    for (int t = 0; t < TM; ++t)
      af[t] = *(const bf8v*)&Ab[(wm + t * 16 + l16) * 32 + rdo];
#pragma unroll
    for (int t = 0; t < TN; ++t)
      bf[t] = *(const bf8v*)&Bb[(wn + t * 16 + l16) * 32 + rdo];
    __builtin_amdgcn_s_setprio(1);
#pragma unroll
    for (int tm = 0; tm < TM / 2; ++tm) {
#pragma unroll
      for (int tn = 0; tn < TN; ++tn)
        acc[tm][tn] = __builtin_amdgcn_mfma_f32_16x16x32_bf16(
            af[tm], bf[tn], acc[tm][tn], 0, 0, 0);
      if (EPI == 3)
        accr[tm] = __builtin_amdgcn_mfma_f32_16x16x32_bf16(
            af[tm], ones, accr[tm], 0, 0, 0);
    }
    __builtin_amdgcn_s_setprio(0);
    __builtin_amdgcn_s_barrier();
    stageB(d + 3);
    __builtin_amdgcn_s_setprio(1);
#pragma unroll
    for (int tm = TM / 2; tm < TM; ++tm) {
#pragma unroll
      for (int tn = 0; tn < TN; ++tn)
        acc[tm][tn] = __builtin_amdgcn_mfma_f32_16x16x32_bf16(
            af[tm], bf[tn], acc[tm][tn], 0, 0, 0);
      if (EPI == 3)
        accr[tm] = __builtin_amdgcn_mfma_f32_16x16x32_bf16(
            af[tm], ones, accr[tm], 0, 0, 0);
    }
    __builtin_amdgcn_s_setprio(0);
  };

  // prologue: stage chunks 0..2 (A then B, in order)
  stageA(0); stageB(0); stageA(1); stageB(1); stageA(2); stageB(2);

  int d = 0;
  for (; d < nchunk - 2; ++d) {
    if constexpr (VN == 8) asm volatile("s_waitcnt vmcnt(8)" ::: "memory");
    else                   asm volatile("s_waitcnt vmcnt(6)" ::: "memory");
    body(d);
  }
  if constexpr (VN == 8) asm volatile("s_waitcnt vmcnt(4)" ::: "memory");
  else                   asm volatile("s_waitcnt vmcnt(3)" ::: "memory");
  body(d); ++d;
  asm volatile("s_waitcnt vmcnt(0)" ::: "memory");
  body(d);

  // C/D layout (verified m89/m91): col = lane&15, row = quad*4 + reg
  if (EPI == 2) {
#pragma unroll
    for (int tm = 0; tm < TM; ++tm) {
#pragma unroll
      for (int r = 0; r < 4; ++r) {
        const int row = m0 + wm + tm * 16 + quad * 4 + r;
#pragma unroll
        for (int tn = 0; tn < TN; ++tn) {
          const int col = n0 + wn + tn * 16 + l16;
          float e = __expf(acc[tm][tn][r] * 0.044194173824159216f);
          ((unsigned short*)Cp)[(long)bz * sC + (long)row * Nn + col] = f2bf(e);
        }
      }
    }
  } else if (EPI == 3) {
#pragma unroll
    for (int tm = 0; tm < TM; ++tm) {
#pragma unroll
      for (int r = 0; r < 4; ++r) {
        const int row = m0 + wm + tm * 16 + quad * 4 + r;
        const float inv = 1.0f / accr[tm][r];
#pragma unroll
        for (int tn = 0; tn < TN; ++tn) {
          const int col = n0 + wn + tn * 16 + l16;
          ((unsigned short*)Cp)[(long)bz * sC + (long)row * Nn + col] =
              f2bf(acc[tm][tn][r] * inv);
        }
      }
    }
  } else {
#pragma unroll
    for (int tm = 0; tm < TM; ++tm) {
#pragma unroll
      for (int tn = 0; tn < TN; ++tn) {
        const int col = n0 + wn + tn * 16 + l16;
#pragma unroll
        for (int r = 0; r < 4; ++r) {
          const int row = m0 + wm + tm * 16 + quad * 4 + r;
          float val = acc[tm][tn][r];
          if (EPI == 0) {
            val += bias[col];
            ((unsigned short*)Cp)[(long)bz * sC + (long)row * Nn + col] = f2bf(val);
          } else if (EPI == 1) {
            val += bias[row];
            ((unsigned short*)Cp)[(long)bz * sC + (long)row * Nn + col] = f2bf(val);
          } else {
            ((float*)Cp)[(long)bz * sC + (long)row * Nn + col] =
                val + bias[row] + X[(long)bz * sX + (long)row * Nn + col];
          }
        }
      }
    }
  }
}

extern "C" void kernel_launch(void* const* d_in, const int* in_sizes, int n_in,
                              void* d_out, int out_size, void* d_ws, size_t ws_size,
                              hipStream_t stream) {
  (void)in_sizes; (void)n_in; (void)out_size;
  const float* x  = (const float*)d_in[0];
  const float* gs = (const float*)d_in[1];
  const float* gb = (const float*)d_in[2];
  const float* wq = (const float*)d_in[3];
  const float* bq = (const float*)d_in[4];
  const float* wk = (const float*)d_in[5];
  const float* bk = (const float*)d_in[6];
  const float* wv = (const float*)d_in[7];
  const float* bv = (const float*)d_in[8];
  const float* wp = (const float*)d_in[9];
  const float* bp = (const float*)d_in[10];
  float* out = (float*)d_out;

  char* ws = (char*)d_ws;
  const long NC  = (long)NDIM * CDIM;        // per-batch [N,C] elems
  const long NQK = (long)NDIM * 1024;        // per-batch [N,1024] elems
  const long BUF = NC * 2 * BATCH;           // [B,N,C] bf16 buffer = 16,777,216 B
  const long NN  = (long)NDIM * NDIM;

  // Layout (aliased):
  //   [0, BUF)        hT, later OT
  //   [BUF, 3BUF)     qkT [B,N,1024]; later wpb overlays its head
  //   [3BUF, 4BUF)    vB [B,C,N]
  //   [4BUF, ...)     sc: bf16 unnormalized exp-scores P'; head doubles as
  //                   wqkb/wvb/bqk/stats (all dead before scores GEMM writes)
  unsigned short* hT   = (unsigned short*)(ws);
  unsigned short* OT   = hT;
  unsigned short* qkT  = (unsigned short*)(ws + BUF);
  unsigned short* vB   = (unsigned short*)(ws + BUF * 3);
  unsigned short* sc   = (unsigned short*)(ws + BUF * 4);
  unsigned short* wqkb = sc;                                   // 1 MB
  unsigned short* wvb  = (unsigned short*)(ws + BUF * 4 + 1048576);
  float* bqk           = (float*)(ws + BUF * 4 + 1572864);
  float* stats         = (float*)(ws + BUF * 4 + 1581056);
  unsigned short* wpb  = qkT;  // overlays dead qkT for final proj

  gn_stats_kernel<<<BATCH * 32, 256, 0, stream>>>(x, stats);
  gn_transpose_kernel<<<dim3(NDIM / 64, CDIM / 64, BATCH), 256, 0, stream>>>(x, gs, gb, stats, hT);
  prep_kernel<<<769, 256, 0, stream>>>(wq, wk, wv, bq, bk, wqkb, wvb, bqk);

  // qkT = hT * [wq;wk]^T + bqk  ([N,1024]) : 4x16x4 tiles = 256 blocks
  gemm8<256, 256, 0, 0><<<256, 512, 0, stream>>>(
      hT, NC, CDIM, wqkb, 0, CDIM, qkT, NQK, bqk, nullptr, 0, 4, 16, 1024, CDIM);
  // v = wv * hT^T + bv  ([C,N]) : 16x4x4 = 256 blocks
  gemm8<128, 256, 1, 1><<<256, 512, 0, stream>>>(
      wvb, 0, CDIM, hT, NC, CDIM, vB, NC, bv, nullptr, 0, 16, 4, NDIM, CDIM);

  if (ws_size >= (size_t)(BUF * 4) + (size_t)(NN * 2) * BATCH) {
    // Primary (192 MiB): fully batched attention, softmax fused away.
    gemm8<256, 256, 2, 0><<<1024, 512, 0, stream>>>(
        qkT, NQK, 1024, qkT + 512, NQK, 1024, sc, NN, nullptr, nullptr, 0,
        16, 16, NDIM, CDIM);
    gemm8<128, 256, 3, 1><<<256, 512, 0, stream>>>(
        sc, NN, NDIM, vB, NC, NDIM, OT, NC, nullptr, nullptr, 0,
        2, 32, CDIM, NDIM);
  } else {
    // Fallback (~101 MB): per-batch rounds.
    for (int b = 0; b < BATCH; ++b) {
      gemm8<256, 256, 2, 0><<<256, 512, 0, stream>>>(
          qkT + b * NQK, 0, 1024, qkT + b * NQK + 512, 0, 1024, sc, 0,
          nullptr, nullptr, 0, 16, 16, NDIM, CDIM);
      gemm8<128, 256, 3, 1><<<64, 512, 0, stream>>>(
          sc, 0, NDIM, vB + b * NC, 0, NDIM, OT + b * NC, 0,
          nullptr, nullptr, 0, 2, 32, CDIM, NDIM);
    }
  }

  // out = wp * OT^T + bp + x  (fp32 out, fused residual); wpb overlays dead qkT
  cvt_kernel<<<256, 256, 0, stream>>>(wp, wpb, 65536);
  gemm8<128, 256, 4, 1><<<256, 512, 0, stream>>>(
      wpb, 0, CDIM, OT, NC, CDIM, out, NC, bp, x, NC, 16, 4, NDIM, CDIM);
}

// Round 2
// 413.160 us; speedup vs baseline: 1.0335x; 1.0335x over previous
//
#include <hip/hip_runtime.h>

#define CDIM 512
#define NDIM 4096
#define BATCH 4

using bf8v = __attribute__((ext_vector_type(8))) __bf16;
using f4v  = __attribute__((ext_vector_type(4))) float;

typedef __attribute__((address_space(1))) unsigned int gu32;
typedef __attribute__((address_space(3))) unsigned int lu32;

static __device__ __forceinline__ unsigned short f2bf(float f) {
  unsigned int u = __float_as_uint(f);
  u += 0x7fffu + ((u >> 16) & 1u);   // round-to-nearest-even
  return (unsigned short)(u >> 16);
}

// ---------------- GN pass 1: per-(b,g) mean/rstd ----------------
__global__ __launch_bounds__(256) void gn_stats_kernel(
    const float* __restrict__ x, float* __restrict__ stats) {
  const int tid = threadIdx.x;
  const float4* xv = (const float4*)(x + (long)blockIdx.x * 65536);
  float s = 0.f, ss = 0.f;
  for (int i = tid; i < 16384; i += 256) {
    float4 d = xv[i];
    s  += d.x + d.y + d.z + d.w;
    ss += d.x * d.x + d.y * d.y + d.z * d.z + d.w * d.w;
  }
#pragma unroll
  for (int off = 32; off; off >>= 1) {
    s  += __shfl_down(s, off);
    ss += __shfl_down(ss, off);
  }
  __shared__ float red[8];
  if ((tid & 63) == 0) { red[tid >> 6] = s; red[4 + (tid >> 6)] = ss; }
  __syncthreads();
  if (tid == 0) {
    float S  = red[0] + red[1] + red[2] + red[3];
    float SS = red[4] + red[5] + red[6] + red[7];
    float mean = S * (1.f / 65536.f);
    float var  = SS * (1.f / 65536.f) - mean * mean;
    stats[blockIdx.x * 2]     = mean;
    stats[blockIdx.x * 2 + 1] = rsqrtf(var + 1e-6f);
  }
}

// ---------------- GN pass 2: normalize + transpose, fp32 [C,N] -> bf16 [N,C] ----------------
__global__ __launch_bounds__(256) void gn_transpose_kernel(
    const float* __restrict__ x, const float* __restrict__ gs,
    const float* __restrict__ gb, const float* __restrict__ stats,
    unsigned short* __restrict__ hT) {
  __shared__ float t[64][65];
  const int tid = threadIdx.x;
  const int b = blockIdx.z;
  const long bbx = (long)b * ((long)CDIM * NDIM);
  const int n0 = blockIdx.x * 64, c0 = blockIdx.y * 64;
  for (int k = 0; k < 4; ++k) {
    int it = tid + k * 256;
    int c = it >> 4, no = (it & 15) << 2;
    int ch = c0 + c;
    int g = ch >> 4;
    float mean = stats[(b * 32 + g) * 2];
    float rstd = stats[(b * 32 + g) * 2 + 1];
    float a  = rstd * gs[ch];
    float bb = gb[ch] - mean * a;
    float4 d = *(const float4*)&x[bbx + (long)ch * NDIM + n0 + no];
    t[no + 0][c] = d.x * a + bb;
    t[no + 1][c] = d.y * a + bb;
    t[no + 2][c] = d.z * a + bb;
    t[no + 3][c] = d.w * a + bb;
  }
  __syncthreads();
  const long bbh = (long)b * ((long)NDIM * CDIM);
  for (int k = 0; k < 2; ++k) {
    int it = tid + k * 256;
    int n = it >> 3, co = (it & 7) << 3;
    unsigned int ow[4];
#pragma unroll
    for (int j = 0; j < 4; ++j) {
      unsigned short lo = f2bf(t[n][co + 2 * j]);
      unsigned short hi = f2bf(t[n][co + 2 * j + 1]);
      ow[j] = (unsigned int)lo | ((unsigned int)hi << 16);
    }
    uint4 o; o.x = ow[0]; o.y = ow[1]; o.z = ow[2]; o.w = ow[3];
    *(uint4*)&hT[bbh + (long)(n0 + n) * CDIM + c0 + co] = o;
  }
}

// ---------------- merged prep: wq/wk/wv fp32->bf16 + bias concat ----------------
__global__ __launch_bounds__(256) void prep_kernel(
    const float* __restrict__ wq, const float* __restrict__ wk,
    const float* __restrict__ wv, const float* __restrict__ bq,
    const float* __restrict__ bk, unsigned short* __restrict__ wqkb,
    unsigned short* __restrict__ wvb, float* __restrict__ bqk) {
  int blk = blockIdx.x;
  if (blk < 768) {
    int i = blk * 256 + threadIdx.x;
    const float* src = (blk < 256) ? wq : (blk < 512) ? wk : wv;
    unsigned short* dst = (blk < 256) ? wqkb : (blk < 512) ? (wqkb + 262144) : wvb;
    int j = i - ((blk < 256) ? 0 : (blk < 512) ? 65536 : 131072);
    float4 d = ((const float4*)src)[j];
    ushort4 o;
    o.x = f2bf(d.x); o.y = f2bf(d.y); o.z = f2bf(d.z); o.w = f2bf(d.w);
    ((ushort4*)dst)[j] = o;
  } else {
#pragma unroll
    for (int k = 0; k < 4; ++k) {
      int i = threadIdx.x + k * 256;
      bqk[i] = (i < 512) ? bq[i] : bk[i - 512];
    }
  }
}

// ---------------- fp32 -> bf16 convert (wp, launched late) ----------------
__global__ __launch_bounds__(256) void cvt_kernel(
    const float* __restrict__ src, unsigned short* __restrict__ dst, int n4) {
  int i = blockIdx.x * 256 + threadIdx.x;
  if (i >= n4) return;
  float4 d = ((const float4*)src)[i];
  ushort4 o;
  o.x = f2bf(d.x); o.y = f2bf(d.y); o.z = f2bf(d.z); o.w = f2bf(d.w);
  ((ushort4*)dst)[i] = o;
}

// ---------------- 8-phase NT GEMM, 8 waves, 4-slot LDS ring, counted vmcnt ----------------
// C[M,Nn] = A[M,K] * B[Nn,K]^T, bf16 operands, row strides lA/lB.
// K consumed in 32-wide chunks; chunk c lives in LDS ring slot c&3; staged 3
// chunks ahead via global_load_lds; per chunk two phases, each: [wait+]barrier,
// stage one operand of chunk d+3, ds_read frags (phase A only), setprio(1),
// MFMA half-cluster, setprio(0).  vmcnt is counted (8 or 6), drained 4->0 only
// in the last two chunks.
// LDS swizzle: rows are 64 B (16 dwords), so the 4-bank-group index is
// 16*(row&1) + 4*granule.  XOR key must therefore be (row>>1)&3 (NOT row&3,
// which left only 4 distinct groups per 16-lane service group = 4-way
// conflict, measured 8.4M cycles in round 1).  With key=(row>>1)&3 each
// 16-lane group covers all 8 groups x 2 lanes = conflict-free (m136: 2-way
// free).  Same involution on the staging *source* granule (rule #21).
// EPI: 0 bf16 + bias[col]; 1 bf16 + bias[row]; 2 bf16 exp(val*scale);
//      3 bf16 val/rowsum (ones-MFMA); 4 fp32 + bias[row] + residual X.
// ORD: 0 = bx fastest in g, 1 = by fastest (L2 panel-reuse choice).
template <int BM, int BN, int EPI, int ORD>
__global__ __launch_bounds__(512, 2) void gemm8(
    const unsigned short* __restrict__ A, long sA, int lA,
    const unsigned short* __restrict__ B, long sB, int lB,
    void* __restrict__ Cp, long sC,
    const float* __restrict__ bias,
    const float* __restrict__ X, long sX,
    int GX, int GY, int Nn, int K) {
  constexpr int TM = BM / 32;          // frag rows per wave (8 or 4)
  constexpr int TN = BN / 64;          // frag cols per wave (4)
  constexpr int LA = BM / 128;         // global_load_lds per thread per A-chunk
  constexpr int LB = BN / 128;
  constexpr int VN = 2 * (LA + LB);    // steady-state vmcnt (8 or 6)

  __shared__ __align__(16) unsigned short As[4 * BM * 32];
  __shared__ __align__(16) unsigned short Bs[4 * BN * 32];

  const int tid = threadIdx.x;
  const int nwg = gridDim.x;
  // bijective XCD-chunk mapping (nwg % 8 == 0 for all launches)
  const int g = (blockIdx.x & 7) * (nwg >> 3) + (blockIdx.x >> 3);
  int bx, by, bz;
  if (ORD == 0) { bx = g % GX; int t = g / GX; by = t % GY; bz = t / GY; }
  else          { by = g % GY; int t = g / GY; bx = t % GX; bz = t / GX; }

  A += (long)bz * sA;
  B += (long)bz * sB;
  const int m0 = by * BM;
  const int n0 = bx * BN;
  const int lane = tid & 63;
  const int wv = tid >> 6;
  const int wm = (wv >> 2) * (BM / 2);
  const int wn = (wv & 3) * (BN / 4);
  const int l16 = lane & 15;
  const int quad = lane >> 4;
  const int rdo = ((quad ^ ((l16 >> 1) & 3)) << 3);  // swizzled read granule

  // staging: per load, 512 threads cover 128 rows x 4 granules (16B each)
  const int rl = tid >> 2;             // row within 128-row group
  const int gl = tid & 3;              // physical granule slot
  const int swl = ((gl ^ ((rl >> 1) & 3)) << 3);     // inverse-swizzled source
  const unsigned short* Ag = A + (long)(m0 + rl) * lA + swl;
  const unsigned short* Bg = B + (long)(n0 + rl) * lB + swl;
  unsigned short* Asl = As + wv * 512;         // wave-uniform LDS dest base
  unsigned short* Bsl = Bs + wv * 512;

  const int nchunk = K >> 5;

  auto stageA = [&](int c) {
    if (c < nchunk) {
#pragma unroll
      for (int i = 0; i < LA; ++i)
        __builtin_amdgcn_global_load_lds(
            (const gu32*)(Ag + (long)i * 128 * lA + c * 32),
            (lu32*)(Asl + (c & 3) * (BM * 32) + i * 4096), 16, 0, 0);
    }
  };
  auto stageB = [&](int c) {
    if (c < nchunk) {
#pragma unroll
      for (int i = 0; i < LB; ++i)
        __builtin_amdgcn_global_load_lds(
            (const gu32*)(Bg + (long)i * 128 * lB + c * 32),
            (lu32*)(Bsl + (c & 3) * (BN * 32) + i * 4096), 16, 0, 0);
    }
  };

  f4v acc[TM][TN] = {};
  f4v accr[TM] = {};                   // EPI==3 row-sums (DCE'd otherwise)
  bf8v ones;
#pragma unroll
  for (int i = 0; i < 8; ++i) ones[i] = (__bf16)1.0f;

  auto body = [&](int d) {
    __builtin_amdgcn_s_barrier();
    stageA(d + 3);
    const unsigned short* Ab = As + (d & 3) * (BM * 32);
    const unsigned short* Bb = Bs + (d & 3) * (BN * 32);
    bf8v af[TM], bf[TN];
    // read order: A-half1, all B, A-half2 — lets the compiler start the
    // first MFMA half without waiting on the second half's A reads.
#pragma unroll
    for (int t = 0; t < TM / 2; ++t)
      af[t] = *(const bf8v*)&Ab[(wm + t * 16 + l16) * 32 + rdo];
#pragma unroll
    for (int t = 0; t < TN; ++t)
      bf[t] = *(const bf8v*)&Bb[(wn + t * 16 + l16) * 32 + rdo];
#pragma unroll
    for (int t = TM / 2; t < TM; ++t)
      af[t] = *(const bf8v*)&Ab[(wm + t * 16 + l16) * 32 + rdo];
    __builtin_amdgcn_s_setprio(1);
#pragma unroll
    for (int tm = 0; tm < TM / 2; ++tm) {
#pragma unroll
      for (int tn = 0; tn < TN; ++tn)
        acc[tm][tn] = __builtin_amdgcn_mfma_f32_16x16x32_bf16(
            af[tm], bf[tn], acc[tm][tn], 0, 0, 0);
      if (EPI == 3)
        accr[tm] = __builtin_amdgcn_mfma_f32_16x16x32_bf16(
            af[tm], ones, accr[tm], 0, 0, 0);
    }
    __builtin_amdgcn_s_setprio(0);
    __builtin_amdgcn_s_barrier();
    stageB(d + 3);
    __builtin_amdgcn_s_setprio(1);
#pragma unroll
    for (int tm = TM / 2; tm < TM; ++tm) {
#pragma unroll
      for (int tn = 0; tn < TN; ++tn)
        acc[tm][tn] = __builtin_amdgcn_mfma_f32_16x16x32_bf16(
            af[tm], bf[tn], acc[tm][tn], 0, 0, 0);
      if (EPI == 3)
        accr[tm] = __builtin_amdgcn_mfma_f32_16x16x32_bf16(
            af[tm], ones, accr[tm], 0, 0, 0);
    }
    __builtin_amdgcn_s_setprio(0);
  };

  // prologue: stage chunks 0..2 (A then B, in order)
  stageA(0); stageB(0); stageA(1); stageB(1); stageA(2); stageB(2);

  int d = 0;
  for (; d < nchunk - 2; ++d) {
    if constexpr (VN == 8) asm volatile("s_waitcnt vmcnt(8)" ::: "memory");
    else                   asm volatile("s_waitcnt vmcnt(6)" ::: "memory");
    body(d);
  }
  if constexpr (VN == 8) asm volatile("s_waitcnt vmcnt(4)" ::: "memory");
  else                   asm volatile("s_waitcnt vmcnt(3)" ::: "memory");
  body(d); ++d;
  asm volatile("s_waitcnt vmcnt(0)" ::: "memory");
  body(d);

  // C/D layout (verified m89/m91): col = lane&15, row = quad*4 + reg
  if (EPI == 2) {
#pragma unroll
    for (int tm = 0; tm < TM; ++tm) {
#pragma unroll
      for (int r = 0; r < 4; ++r) {
        const int row = m0 + wm + tm * 16 + quad * 4 + r;
#pragma unroll
        for (int tn = 0; tn < TN; ++tn) {
          const int col = n0 + wn + tn * 16 + l16;
          float e = __expf(acc[tm][tn][r] * 0.044194173824159216f);
          ((unsigned short*)Cp)[(long)bz * sC + (long)row * Nn + col] = f2bf(e);
        }
      }
    }
  } else if (EPI == 3) {
#pragma unroll
    for (int tm = 0; tm < TM; ++tm) {
#pragma unroll
      for (int r = 0; r < 4; ++r) {
        const int row = m0 + wm + tm * 16 + quad * 4 + r;
        const float inv = 1.0f / accr[tm][r];
#pragma unroll
        for (int tn = 0; tn < TN; ++tn) {
          const int col = n0 + wn + tn * 16 + l16;
          ((unsigned short*)Cp)[(long)bz * sC + (long)row * Nn + col] =
              f2bf(acc[tm][tn][r] * inv);
        }
      }
    }
  } else {
#pragma unroll
    for (int tm = 0; tm < TM; ++tm) {
#pragma unroll
      for (int tn = 0; tn < TN; ++tn) {
        const int col = n0 + wn + tn * 16 + l16;
#pragma unroll
        for (int r = 0; r < 4; ++r) {
          const int row = m0 + wm + tm * 16 + quad * 4 + r;
          float val = acc[tm][tn][r];
          if (EPI == 0) {
            val += bias[col];
            ((unsigned short*)Cp)[(long)bz * sC + (long)row * Nn + col] = f2bf(val);
          } else if (EPI == 1) {
            val += bias[row];
            ((unsigned short*)Cp)[(long)bz * sC + (long)row * Nn + col] = f2bf(val);
          } else {
            ((float*)Cp)[(long)bz * sC + (long)row * Nn + col] =
                val + bias[row] + X[(long)bz * sX + (long)row * Nn + col];
          }
        }
      }
    }
  }
}

extern "C" void kernel_launch(void* const* d_in, const int* in_sizes, int n_in,
                              void* d_out, int out_size, void* d_ws, size_t ws_size,
                              hipStream_t stream) {
  (void)in_sizes; (void)n_in; (void)out_size;
  const float* x  = (const float*)d_in[0];
  const float* gs = (const float*)d_in[1];
  const float* gb = (const float*)d_in[2];
  const float* wq = (const float*)d_in[3];
  const float* bq = (const float*)d_in[4];
  const float* wk = (const float*)d_in[5];
  const float* bk = (const float*)d_in[6];
  const float* wv = (const float*)d_in[7];
  const float* bv = (const float*)d_in[8];
  const float* wp = (const float*)d_in[9];
  const float* bp = (const float*)d_in[10];
  float* out = (float*)d_out;

  char* ws = (char*)d_ws;
  const long NC  = (long)NDIM * CDIM;        // per-batch [N,C] elems
  const long NQK = (long)NDIM * 1024;        // per-batch [N,1024] elems
  const long BUF = NC * 2 * BATCH;           // [B,N,C] bf16 buffer = 16,777,216 B
  const long NN  = (long)NDIM * NDIM;

  // Layout (aliased):
  //   [0, BUF)        hT, later OT
  //   [BUF, 3BUF)     qkT [B,N,1024]; later wpb overlays its head
  //   [3BUF, 4BUF)    vB [B,C,N]
  //   [4BUF, ...)     sc: bf16 unnormalized exp-scores P'; head doubles as
  //                   wqkb/wvb/bqk/stats (all dead before scores GEMM writes)
  unsigned short* hT   = (unsigned short*)(ws);
  unsigned short* OT   = hT;
  unsigned short* qkT  = (unsigned short*)(ws + BUF);
  unsigned short* vB   = (unsigned short*)(ws + BUF * 3);
  unsigned short* sc   = (unsigned short*)(ws + BUF * 4);
  unsigned short* wqkb = sc;                                   // 1 MB
  unsigned short* wvb  = (unsigned short*)(ws + BUF * 4 + 1048576);
  float* bqk           = (float*)(ws + BUF * 4 + 1572864);
  float* stats         = (float*)(ws + BUF * 4 + 1581056);
  unsigned short* wpb  = qkT;  // overlays dead qkT for final proj

  gn_stats_kernel<<<BATCH * 32, 256, 0, stream>>>(x, stats);
  gn_transpose_kernel<<<dim3(NDIM / 64, CDIM / 64, BATCH), 256, 0, stream>>>(x, gs, gb, stats, hT);
  prep_kernel<<<769, 256, 0, stream>>>(wq, wk, wv, bq, bk, wqkb, wvb, bqk);

  // qkT = hT * [wq;wk]^T + bqk  ([N,1024]) : 4x16x4 tiles = 256 blocks
  gemm8<256, 256, 0, 0><<<256, 512, 0, stream>>>(
      hT, NC, CDIM, wqkb, 0, CDIM, qkT, NQK, bqk, nullptr, 0, 4, 16, 1024, CDIM);
  // v = wv * hT^T + bv  ([C,N]) : 16x4x4 = 256 blocks
  gemm8<128, 256, 1, 1><<<256, 512, 0, stream>>>(
      wvb, 0, CDIM, hT, NC, CDIM, vB, NC, bv, nullptr, 0, 16, 4, NDIM, CDIM);

  if (ws_size >= (size_t)(BUF * 4) + (size_t)(NN * 2) * BATCH) {
    // Primary (192 MiB): fully batched attention, softmax fused away.
    gemm8<256, 256, 2, 0><<<1024, 512, 0, stream>>>(
        qkT, NQK, 1024, qkT + 512, NQK, 1024, sc, NN, nullptr, nullptr, 0,
        16, 16, NDIM, CDIM);
    gemm8<128, 256, 3, 1><<<256, 512, 0, stream>>>(
        sc, NN, NDIM, vB, NC, NDIM, OT, NC, nullptr, nullptr, 0,
        2, 32, CDIM, NDIM);
  } else {
    // Fallback (~101 MB): per-batch rounds.
    for (int b = 0; b < BATCH; ++b) {
      gemm8<256, 256, 2, 0><<<256, 512, 0, stream>>>(
          qkT + b * NQK, 0, 1024, qkT + b * NQK + 512, 0, 1024, sc, 0,
          nullptr, nullptr, 0, 16, 16, NDIM, CDIM);
      gemm8<128, 256, 3, 1><<<64, 512, 0, stream>>>(
          sc, 0, NDIM, vB + b * NC, 0, NDIM, OT + b * NC, 0,
          nullptr, nullptr, 0, 2, 32, CDIM, NDIM);
    }
  }

  // out = wp * OT^T + bp + x  (fp32 out, fused residual); wpb overlays dead qkT
  cvt_kernel<<<256, 256, 0, stream>>>(wp, wpb, 65536);
  gemm8<128, 256, 4, 1><<<256, 512, 0, stream>>>(
      wpb, 0, CDIM, OT, NC, CDIM, out, NC, bp, x, NC, 16, 4, NDIM, CDIM);
}

// Round 3
// 358.491 us; speedup vs baseline: 1.1911x; 1.1525x over previous
//
#include <hip/hip_runtime.h>

#define CDIM 512
#define NDIM 4096
#define BATCH 4

using bf8v = __attribute__((ext_vector_type(8))) __bf16;
using f4v  = __attribute__((ext_vector_type(4))) float;

typedef __attribute__((address_space(1))) unsigned int gu32;
typedef __attribute__((address_space(3))) unsigned int lu32;

static __device__ __forceinline__ unsigned short f2bf(float f) {
  unsigned int u = __float_as_uint(f);
  u += 0x7fffu + ((u >> 16) & 1u);   // round-to-nearest-even
  return (unsigned short)(u >> 16);
}

// inline-asm LDS read: invisible to SIInsertWaitcnts' LDS-DMA tracking, so no
// conservative vmcnt(0) is inserted while global_load_lds prefetches are in
// flight.  Correctness of the data is guaranteed by the explicit counted
// vmcnt + barrier protocol in the K-loop.  LDS byte offset = low 32 bits of
// the generic pointer (shared aperture has zero low half).
static __device__ __forceinline__ bf8v lds_read16(const unsigned short* p) {
  bf8v r;
  unsigned off = (unsigned)(unsigned long long)p;
  asm volatile("ds_read_b128 %0, %1" : "=v"(r) : "v"(off));
  return r;
}

// ---------------- GN pass 1: per-(b,g) mean/rstd ----------------
__global__ __launch_bounds__(256) void gn_stats_kernel(
    const float* __restrict__ x, float* __restrict__ stats) {
  const int tid = threadIdx.x;
  const float4* xv = (const float4*)(x + (long)blockIdx.x * 65536);
  float s = 0.f, ss = 0.f;
  for (int i = tid; i < 16384; i += 256) {
    float4 d = xv[i];
    s  += d.x + d.y + d.z + d.w;
    ss += d.x * d.x + d.y * d.y + d.z * d.z + d.w * d.w;
  }
#pragma unroll
  for (int off = 32; off; off >>= 1) {
    s  += __shfl_down(s, off);
    ss += __shfl_down(ss, off);
  }
  __shared__ float red[8];
  if ((tid & 63) == 0) { red[tid >> 6] = s; red[4 + (tid >> 6)] = ss; }
  __syncthreads();
  if (tid == 0) {
    float S  = red[0] + red[1] + red[2] + red[3];
    float SS = red[4] + red[5] + red[6] + red[7];
    float mean = S * (1.f / 65536.f);
    float var  = SS * (1.f / 65536.f) - mean * mean;
    stats[blockIdx.x * 2]     = mean;
    stats[blockIdx.x * 2 + 1] = rsqrtf(var + 1e-6f);
  }
}

// ---------------- GN pass 2: normalize + transpose, fp32 [C,N] -> bf16 [N,C] ----------------
__global__ __launch_bounds__(256) void gn_transpose_kernel(
    const float* __restrict__ x, const float* __restrict__ gs,
    const float* __restrict__ gb, const float* __restrict__ stats,
    unsigned short* __restrict__ hT) {
  __shared__ float t[64][65];
  const int tid = threadIdx.x;
  const int b = blockIdx.z;
  const long bbx = (long)b * ((long)CDIM * NDIM);
  const int n0 = blockIdx.x * 64, c0 = blockIdx.y * 64;
  for (int k = 0; k < 4; ++k) {
    int it = tid + k * 256;
    int c = it >> 4, no = (it & 15) << 2;
    int ch = c0 + c;
    int g = ch >> 4;
    float mean = stats[(b * 32 + g) * 2];
    float rstd = stats[(b * 32 + g) * 2 + 1];
    float a  = rstd * gs[ch];
    float bb = gb[ch] - mean * a;
    float4 d = *(const float4*)&x[bbx + (long)ch * NDIM + n0 + no];
    t[no + 0][c] = d.x * a + bb;
    t[no + 1][c] = d.y * a + bb;
    t[no + 2][c] = d.z * a + bb;
    t[no + 3][c] = d.w * a + bb;
  }
  __syncthreads();
  const long bbh = (long)b * ((long)NDIM * CDIM);
  for (int k = 0; k < 2; ++k) {
    int it = tid + k * 256;
    int n = it >> 3, co = (it & 7) << 3;
    unsigned int ow[4];
#pragma unroll
    for (int j = 0; j < 4; ++j) {
      unsigned short lo = f2bf(t[n][co + 2 * j]);
      unsigned short hi = f2bf(t[n][co + 2 * j + 1]);
      ow[j] = (unsigned int)lo | ((unsigned int)hi << 16);
    }
    uint4 o; o.x = ow[0]; o.y = ow[1]; o.z = ow[2]; o.w = ow[3];
    *(uint4*)&hT[bbh + (long)(n0 + n) * CDIM + c0 + co] = o;
  }
}

// ---------------- merged prep: wq/wk/wv fp32->bf16 + bias concat ----------------
__global__ __launch_bounds__(256) void prep_kernel(
    const float* __restrict__ wq, const float* __restrict__ wk,
    const float* __restrict__ wv, const float* __restrict__ bq,
    const float* __restrict__ bk, unsigned short* __restrict__ wqkb,
    unsigned short* __restrict__ wvb, float* __restrict__ bqk) {
  int blk = blockIdx.x;
  if (blk < 768) {
    int i = blk * 256 + threadIdx.x;
    const float* src = (blk < 256) ? wq : (blk < 512) ? wk : wv;
    unsigned short* dst = (blk < 256) ? wqkb : (blk < 512) ? (wqkb + 262144) : wvb;
    int j = i - ((blk < 256) ? 0 : (blk < 512) ? 65536 : 131072);
    float4 d = ((const float4*)src)[j];
    ushort4 o;
    o.x = f2bf(d.x); o.y = f2bf(d.y); o.z = f2bf(d.z); o.w = f2bf(d.w);
    ((ushort4*)dst)[j] = o;
  } else {
#pragma unroll
    for (int k = 0; k < 4; ++k) {
      int i = threadIdx.x + k * 256;
      bqk[i] = (i < 512) ? bq[i] : bk[i - 512];
    }
  }
}

// ---------------- fp32 -> bf16 convert (wp, launched late) ----------------
__global__ __launch_bounds__(256) void cvt_kernel(
    const float* __restrict__ src, unsigned short* __restrict__ dst, int n4) {
  int i = blockIdx.x * 256 + threadIdx.x;
  if (i >= n4) return;
  float4 d = ((const float4*)src)[i];
  ushort4 o;
  o.x = f2bf(d.x); o.y = f2bf(d.y); o.z = f2bf(d.z); o.w = f2bf(d.w);
  ((ushort4*)dst)[i] = o;
}

// ---------------- pipelined NT GEMM, 8 waves, 4-slot LDS ring, counted vmcnt ----------------
// C[M,Nn] = A[M,K] * B[Nn,K]^T, bf16 operands, row strides lA/lB.
// K in 32-wide chunks; chunk c lives in ring slot c&3, staged 3 chunks ahead
// via global_load_lds.  Per chunk: wait vmcnt(VN) -> s_barrier -> stage(d+3)
// -> inline-asm ds_read frags (slot d) -> lgkmcnt(0) -> sched_barrier(0) ->
// setprio(1) MFMA cluster setprio(0).  No "memory" clobbers anywhere in the
// loop: a memory clobber (or visible-IR ds_read with pending LDS-DMA) makes
// SIInsertWaitcnts emit a conservative s_waitcnt vmcnt(0), serializing every
// chunk on HBM latency (rounds 1-2: MfmaUtil stuck at 28%, 2290 cyc/chunk).
// Safety: at the wait, the wave's own chunk-d stages are complete (VN = 2
// chunk-pairs in flight); the barrier extends that to all waves; slot
// (d+3)&3 overwrite is safe because every wave finished reading that slot
// (lgkmcnt(0)) before reaching the preceding barrier.
// LDS swizzle: rows are 64 B; 4-bank-group index = 16*(row&1) + 4*granule,
// so XOR key = (row>>1)&3 on both staging source and read (round 2: 0
// conflicts).
// EPI: 0 bf16 + bias[col]; 1 bf16 + bias[row]; 2 bf16 exp(val*scale);
//      3 bf16 val/rowsum (ones-MFMA); 4 fp32 + bias[row] + residual X.
// ORD: 0 = bx fastest in g, 1 = by fastest (L2 panel-reuse choice).
template <int BM, int BN, int EPI, int ORD>
__global__ __launch_bounds__(512, 2) void gemm8(
    const unsigned short* __restrict__ A, long sA, int lA,
    const unsigned short* __restrict__ B, long sB, int lB,
    void* __restrict__ Cp, long sC,
    const float* __restrict__ bias,
    const float* __restrict__ X, long sX,
    int GX, int GY, int Nn, int K) {
  constexpr int TM = BM / 32;          // frag rows per wave (8 or 4)
  constexpr int TN = BN / 64;          // frag cols per wave (4)
  constexpr int LA = BM / 128;         // global_load_lds per thread per A-chunk
  constexpr int LB = BN / 128;
  constexpr int VN = 2 * (LA + LB);    // steady-state vmcnt (8 or 6)

  __shared__ __align__(16) unsigned short As[4 * BM * 32];
  __shared__ __align__(16) unsigned short Bs[4 * BN * 32];

  const int tid = threadIdx.x;
  const int nwg = gridDim.x;
  // bijective XCD-chunk mapping (nwg % 8 == 0 for all launches)
  const int g = (blockIdx.x & 7) * (nwg >> 3) + (blockIdx.x >> 3);
  int bx, by, bz;
  if (ORD == 0) { bx = g % GX; int t = g / GX; by = t % GY; bz = t / GY; }
  else          { by = g % GY; int t = g / GY; bx = t % GX; bz = t / GX; }

  A += (long)bz * sA;
  B += (long)bz * sB;
  const int m0 = by * BM;
  const int n0 = bx * BN;
  const int lane = tid & 63;
  const int wv = tid >> 6;
  const int wm = (wv >> 2) * (BM / 2);
  const int wn = (wv & 3) * (BN / 4);
  const int l16 = lane & 15;
  const int quad = lane >> 4;
  const int rdo = ((quad ^ ((l16 >> 1) & 3)) << 3);  // swizzled read granule

  // staging: per load, 512 threads cover 128 rows x 4 granules (16B each)
  const int rl = tid >> 2;             // row within 128-row group
  const int gl = tid & 3;              // physical granule slot
  const int swl = ((gl ^ ((rl >> 1) & 3)) << 3);     // inverse-swizzled source
  const unsigned short* Ag = A + (long)(m0 + rl) * lA + swl;
  const unsigned short* Bg = B + (long)(n0 + rl) * lB + swl;
  unsigned short* Asl = As + wv * 512;         // wave-uniform LDS dest base
  unsigned short* Bsl = Bs + wv * 512;

  const int nchunk = K >> 5;

  auto stageA = [&](int c) {
    if (c < nchunk) {
#pragma unroll
      for (int i = 0; i < LA; ++i)
        __builtin_amdgcn_global_load_lds(
            (const gu32*)(Ag + (long)i * 128 * lA + c * 32),
            (lu32*)(Asl + (c & 3) * (BM * 32) + i * 4096), 16, 0, 0);
    }
  };
  auto stageB = [&](int c) {
    if (c < nchunk) {
#pragma unroll
      for (int i = 0; i < LB; ++i)
        __builtin_amdgcn_global_load_lds(
            (const gu32*)(Bg + (long)i * 128 * lB + c * 32),
            (lu32*)(Bsl + (c & 3) * (BN * 32) + i * 4096), 16, 0, 0);
    }
  };

  f4v acc[TM][TN] = {};
  f4v accr[TM] = {};                   // EPI==3 row-sums (DCE'd otherwise)
  bf8v ones;
#pragma unroll
  for (int i = 0; i < 8; ++i) ones[i] = (__bf16)1.0f;

  auto body = [&](int d) {
    __builtin_amdgcn_s_barrier();
    stageA(d + 3);
    stageB(d + 3);
    const unsigned short* Ab = As + (d & 3) * (BM * 32);
    const unsigned short* Bb = Bs + (d & 3) * (BN * 32);
    bf8v af[TM], bf[TN];
#pragma unroll
    for (int t = 0; t < TM; ++t)
      af[t] = lds_read16(&Ab[(wm + t * 16 + l16) * 32 + rdo]);
#pragma unroll
    for (int t = 0; t < TN; ++t)
      bf[t] = lds_read16(&Bb[(wn + t * 16 + l16) * 32 + rdo]);
    asm volatile("s_waitcnt lgkmcnt(0)");
    __builtin_amdgcn_sched_barrier(0);
    __builtin_amdgcn_s_setprio(1);
#pragma unroll
    for (int tm = 0; tm < TM; ++tm) {
#pragma unroll
      for (int tn = 0; tn < TN; ++tn)
        acc[tm][tn] = __builtin_amdgcn_mfma_f32_16x16x32_bf16(
            af[tm], bf[tn], acc[tm][tn], 0, 0, 0);
      if (EPI == 3)
        accr[tm] = __builtin_amdgcn_mfma_f32_16x16x32_bf16(
            af[tm], ones, accr[tm], 0, 0, 0);
    }
    __builtin_amdgcn_s_setprio(0);
  };

  // prologue: stage chunks 0..2 (A then B, in order)
  stageA(0); stageB(0); stageA(1); stageB(1); stageA(2); stageB(2);

  int d = 0;
  for (; d < nchunk - 2; ++d) {
    if constexpr (VN == 8) asm volatile("s_waitcnt vmcnt(8)");
    else                   asm volatile("s_waitcnt vmcnt(6)");
    body(d);
  }
  if constexpr (VN == 8) asm volatile("s_waitcnt vmcnt(4)");
  else                   asm volatile("s_waitcnt vmcnt(3)");
  body(d); ++d;
  asm volatile("s_waitcnt vmcnt(0)");
  body(d);

  // C/D layout (verified m89/m91): col = lane&15, row = quad*4 + reg
  if (EPI == 2) {
#pragma unroll
    for (int tm = 0; tm < TM; ++tm) {
#pragma unroll
      for (int r = 0; r < 4; ++r) {
        const int row = m0 + wm + tm * 16 + quad * 4 + r;
#pragma unroll
        for (int tn = 0; tn < TN; ++tn) {
          const int col = n0 + wn + tn * 16 + l16;
          float e = __expf(acc[tm][tn][r] * 0.044194173824159216f);
          ((unsigned short*)Cp)[(long)bz * sC + (long)row * Nn + col] = f2bf(e);
        }
      }
    }
  } else if (EPI == 3) {
#pragma unroll
    for (int tm = 0; tm < TM; ++tm) {
#pragma unroll
      for (int r = 0; r < 4; ++r) {
        const int row = m0 + wm + tm * 16 + quad * 4 + r;
        const float inv = 1.0f / accr[tm][r];
#pragma unroll
        for (int tn = 0; tn < TN; ++tn) {
          const int col = n0 + wn + tn * 16 + l16;
          ((unsigned short*)Cp)[(long)bz * sC + (long)row * Nn + col] =
              f2bf(acc[tm][tn][r] * inv);
        }
      }
    }
  } else {
#pragma unroll
    for (int tm = 0; tm < TM; ++tm) {
#pragma unroll
      for (int tn = 0; tn < TN; ++tn) {
        const int col = n0 + wn + tn * 16 + l16;
#pragma unroll
        for (int r = 0; r < 4; ++r) {
          const int row = m0 + wm + tm * 16 + quad * 4 + r;
          float val = acc[tm][tn][r];
          if (EPI == 0) {
            val += bias[col];
            ((unsigned short*)Cp)[(long)bz * sC + (long)row * Nn + col] = f2bf(val);
          } else if (EPI == 1) {
            val += bias[row];
            ((unsigned short*)Cp)[(long)bz * sC + (long)row * Nn + col] = f2bf(val);
          } else {
            ((float*)Cp)[(long)bz * sC + (long)row * Nn + col] =
                val + bias[row] + X[(long)bz * sX + (long)row * Nn + col];
          }
        }
      }
    }
  }
}

extern "C" void kernel_launch(void* const* d_in, const int* in_sizes, int n_in,
                              void* d_out, int out_size, void* d_ws, size_t ws_size,
                              hipStream_t stream) {
  (void)in_sizes; (void)n_in; (void)out_size;
  const float* x  = (const float*)d_in[0];
  const float* gs = (const float*)d_in[1];
  const float* gb = (const float*)d_in[2];
  const float* wq = (const float*)d_in[3];
  const float* bq = (const float*)d_in[4];
  const float* wk = (const float*)d_in[5];
  const float* bk = (const float*)d_in[6];
  const float* wv = (const float*)d_in[7];
  const float* bv = (const float*)d_in[8];
  const float* wp = (const float*)d_in[9];
  const float* bp = (const float*)d_in[10];
  float* out = (float*)d_out;

  char* ws = (char*)d_ws;
  const long NC  = (long)NDIM * CDIM;        // per-batch [N,C] elems
  const long NQK = (long)NDIM * 1024;        // per-batch [N,1024] elems
  const long BUF = NC * 2 * BATCH;           // [B,N,C] bf16 buffer = 16,777,216 B
  const long NN  = (long)NDIM * NDIM;

  // Layout (aliased):
  //   [0, BUF)        hT, later OT
  //   [BUF, 3BUF)     qkT [B,N,1024]; later wpb overlays its head
  //   [3BUF, 4BUF)    vB [B,C,N]
  //   [4BUF, ...)     sc: bf16 unnormalized exp-scores P'; head doubles as
  //                   wqkb/wvb/bqk/stats (all dead before scores GEMM writes)
  unsigned short* hT   = (unsigned short*)(ws);
  unsigned short* OT   = hT;
  unsigned short* qkT  = (unsigned short*)(ws + BUF);
  unsigned short* vB   = (unsigned short*)(ws + BUF * 3);
  unsigned short* sc   = (unsigned short*)(ws + BUF * 4);
  unsigned short* wqkb = sc;                                   // 1 MB
  unsigned short* wvb  = (unsigned short*)(ws + BUF * 4 + 1048576);
  float* bqk           = (float*)(ws + BUF * 4 + 1572864);
  float* stats         = (float*)(ws + BUF * 4 + 1581056);
  unsigned short* wpb  = qkT;  // overlays dead qkT for final proj

  gn_stats_kernel<<<BATCH * 32, 256, 0, stream>>>(x, stats);
  gn_transpose_kernel<<<dim3(NDIM / 64, CDIM / 64, BATCH), 256, 0, stream>>>(x, gs, gb, stats, hT);
  prep_kernel<<<769, 256, 0, stream>>>(wq, wk, wv, bq, bk, wqkb, wvb, bqk);

  // qkT = hT * [wq;wk]^T + bqk  ([N,1024]) : 4x16x4 tiles = 256 blocks
  gemm8<256, 256, 0, 0><<<256, 512, 0, stream>>>(
      hT, NC, CDIM, wqkb, 0, CDIM, qkT, NQK, bqk, nullptr, 0, 4, 16, 1024, CDIM);
  // v = wv * hT^T + bv  ([C,N]) : 16x4x4 = 256 blocks
  gemm8<128, 256, 1, 1><<<256, 512, 0, stream>>>(
      wvb, 0, CDIM, hT, NC, CDIM, vB, NC, bv, nullptr, 0, 16, 4, NDIM, CDIM);

  if (ws_size >= (size_t)(BUF * 4) + (size_t)(NN * 2) * BATCH) {
    // Primary (192 MiB): fully batched attention, softmax fused away.
    gemm8<256, 256, 2, 0><<<1024, 512, 0, stream>>>(
        qkT, NQK, 1024, qkT + 512, NQK, 1024, sc, NN, nullptr, nullptr, 0,
        16, 16, NDIM, CDIM);
    gemm8<128, 256, 3, 1><<<256, 512, 0, stream>>>(
        sc, NN, NDIM, vB, NC, NDIM, OT, NC, nullptr, nullptr, 0,
        2, 32, CDIM, NDIM);
  } else {
    // Fallback (~101 MB): per-batch rounds.
    for (int b = 0; b < BATCH; ++b) {
      gemm8<256, 256, 2, 0><<<256, 512, 0, stream>>>(
          qkT + b * NQK, 0, 1024, qkT + b * NQK + 512, 0, 1024, sc, 0,
          nullptr, nullptr, 0, 16, 16, NDIM, CDIM);
      gemm8<128, 256, 3, 1><<<64, 512, 0, stream>>>(
          sc, 0, NDIM, vB + b * NC, 0, NDIM, OT + b * NC, 0,
          nullptr, nullptr, 0, 2, 32, CDIM, NDIM);
    }
  }

  // out = wp * OT^T + bp + x  (fp32 out, fused residual); wpb overlays dead qkT
  cvt_kernel<<<256, 256, 0, stream>>>(wp, wpb, 65536);
  gemm8<128, 256, 4, 1><<<256, 512, 0, stream>>>(
      wpb, 0, CDIM, OT, NC, CDIM, out, NC, bp, x, NC, 16, 4, NDIM, CDIM);
}